// Round 18
// baseline (29762.601 us; speedup 1.0000x reference)
//
#include <hip/hip_runtime.h>
#include <hip/hip_cooperative_groups.h>
#include <math.h>

namespace cg = cooperative_groups;

#define BATCH 8192
#define KB 2048      // num basis (N of fused GEMM)
#define DD 1024      // dim basis
#define LAM 0.1f
#define N_ITER 100
#define N_POWER 50
#define NTILES 32    // K' = 2048 = 32 * 64  (fp16 1-term: yh vs Gh)

typedef unsigned short u16;
using short8 = __attribute__((ext_vector_type(8))) short;
using f32x4  = __attribute__((ext_vector_type(4))) float;

// ---------- bf16 split helpers (RNE) ----------
__device__ __forceinline__ u16 f2bf(float f) {
  unsigned int u = __builtin_bit_cast(unsigned int, f);
  u = u + 0x7FFFu + ((u >> 16) & 1u);
  return (u16)(u >> 16);
}
__device__ __forceinline__ float bf2f(u16 s) {
  unsigned int u = ((unsigned int)s) << 16;
  return __builtin_bit_cast(float, u);
}

// ---------- fp16 helpers (RNE via HW cvt) ----------
__device__ __forceinline__ u16 f2h(float f) {
  _Float16 h = (_Float16)f;
  return __builtin_bit_cast(unsigned short, h);
}
__device__ __forceinline__ float h2f(u16 s) {
  _Float16 h = __builtin_bit_cast(_Float16, s);
  return (float)h;
}

// ---------------- utility kernels ----------------
__global__ void k_split_f32(const float* __restrict__ in, u16* __restrict__ h,
                            u16* __restrict__ lo, int n) {  // bf16 pair
  for (int i = blockIdx.x * blockDim.x + threadIdx.x; i < n; i += gridDim.x * blockDim.x) {
    float v = in[i];
    u16 hh = f2bf(v);
    h[i] = hh;
    lo[i] = f2bf(v - bf2f(hh));
  }
}

__global__ void k_cvt_f16(const float* __restrict__ in, u16* __restrict__ h, int n) {
  for (int i = blockIdx.x * blockDim.x + threadIdx.x; i < n; i += gridDim.x * blockDim.x)
    h[i] = f2h(in[i]);
}

__global__ void k_zero2(float4* __restrict__ a, int na, float4* __restrict__ b, int nb) {
  float4 z = {0.f, 0.f, 0.f, 0.f};
  for (int i = blockIdx.x * blockDim.x + threadIdx.x; i < na; i += gridDim.x * blockDim.x)
    a[i] = z;
  for (int i = blockIdx.x * blockDim.x + threadIdx.x; i < nb; i += gridDim.x * blockDim.x)
    b[i] = z;
}

// ---------------- fused power iteration (ONE cooperative launch) ----------------
// 64 blocks x 256 thr; 8 threads/row segmenting K. Arithmetic-identical to the
// r17 multi-launch version (same fma nesting, same shfl order, same 64-partial
// sum order); w stays in registers. Tail computes step = 1/L and the mu
// schedule on-device (graph-capture-safe).
__global__ __launch_bounds__(256) void k_power_all(const float* __restrict__ G,
                                                   float* __restrict__ v,
                                                   float* __restrict__ partial,
                                                   float* __restrict__ stepbuf,
                                                   float* __restrict__ mus) {
  cg::grid_group grid = cg::this_grid();
  const int rloc = threadIdx.x >> 3;
  const int seg = threadIdx.x & 7;
  const int row = blockIdx.x * 32 + rloc;
  const int lane = threadIdx.x & 63, wid = threadIdx.x >> 6;
  __shared__ float red[4];

  if (seg == 0) v[row] = 1.f;
  grid.sync();

  for (int st = 0; st < N_POWER + 1; ++st) {
    const float* g = G + (size_t)row * KB + seg * 256;
    const float* vv = v + seg * 256;
    float s = 0.f;
#pragma unroll 8
    for (int j = 0; j < 256; j += 4) {
      float4 gg = *(const float4*)(g + j);
      float4 vx = *(const float4*)(vv + j);
      s = fmaf(gg.x, vx.x, fmaf(gg.y, vx.y, fmaf(gg.z, vx.z, fmaf(gg.w, vx.w, s))));
    }
#pragma unroll
    for (int off = 1; off < 8; off <<= 1) s += __shfl_xor(s, off, 64);
    float val;
    if (st < N_POWER)
      val = (seg == 0) ? s * s : 0.f;          // ||Gv||^2 partial
    else
      val = (seg == 0) ? v[row] * s : 0.f;     // Rayleigh numerator partial
#pragma unroll
    for (int off = 8; off < 64; off <<= 1) val += __shfl_xor(val, off, 64);
    if (lane == 0) red[wid] = val;
    __syncthreads();
    if (threadIdx.x == 0) partial[blockIdx.x] = red[0] + red[1] + red[2] + red[3];
    __syncthreads();
    grid.sync();

    if (st < N_POWER) {
      float n2 = 0.f;
#pragma unroll
      for (int i = 0; i < 64; ++i) n2 += partial[i];
      if (seg == 0) v[row] = s / sqrtf(n2);
      grid.sync();
    } else {
      if (blockIdx.x == 0 && threadIdx.x == 0) {
        float L = 0.f;
#pragma unroll
        for (int i = 0; i < 64; ++i) L += partial[i];
        stepbuf[0] = 1.f / L;
        float t = 1.f;
        for (int it = 0; it < N_ITER; ++it) {
          float tn = 0.5f * (1.f + sqrtf(1.f + 4.f * t * t));
          mus[it] = (t - 1.f) / tn;
          t = tn;
        }
      }
    }
  }
}

// ---------------- split-bf16 MFMA GEMM: C = A @ B^T (r3-proven body) ----------------
// EPI 0: out16[m*N+n] = fp16(acc)   (Cx)
// EPI 1: out32[m*N+n] = acc         (Gram, fp32 for power iteration)
template <int EPI>
__global__ __launch_bounds__(256) void k_xphiT(
    const u16* __restrict__ Ah, const u16* __restrict__ Al,
    const u16* __restrict__ Bh, const u16* __restrict__ Bl,
    u16* __restrict__ out16, float* __restrict__ out32, int N, int K) {
  __shared__ u16 lds[4 * 128 * 32];
  const int tid = threadIdx.x;
  const int w = tid >> 6, l = tid & 63;
  const int row0 = blockIdx.y * 128, col0 = blockIdx.x * 128;
  const int wm = (w >> 1) * 64, wn = (w & 1) * 64;
  const int lrow = l & 15, lk = (l >> 4) * 8;

  f32x4 zero4 = {0.f, 0.f, 0.f, 0.f};
  f32x4 acc[4][4];
#pragma unroll
  for (int i = 0; i < 4; ++i)
#pragma unroll
    for (int j = 0; j < 4; ++j) acc[i][j] = zero4;

  for (int k0 = 0; k0 < K; k0 += 32) {
    {
      const u16* gs[4] = {Ah, Al, Bh, Bl};
      const int r0s[4] = {row0, row0, col0, col0};
#pragma unroll
      for (int st = 0; st < 4; ++st) {
        u16* s = lds + st * 4096;
#pragma unroll
        for (int h = 0; h < 2; ++h) {
          int ch = h * 256 + w * 64 + l;
          const u16* gp = gs[st] + (size_t)(r0s[st] + (ch >> 2)) * K + k0 + (ch & 3) * 8;
          u16* sp = s + (h * 256 + w * 64) * 8;
          __builtin_amdgcn_global_load_lds((const __attribute__((address_space(1))) void*)gp,
                                           (__attribute__((address_space(3))) void*)sp, 16, 0, 0);
        }
      }
    }
    __syncthreads();
    short8 ah[4], al[4];
#pragma unroll
    for (int i = 0; i < 4; ++i) {
      int r = wm + i * 16 + lrow;
      ah[i] = *(const short8*)&lds[0 * 4096 + r * 32 + lk];
      al[i] = *(const short8*)&lds[1 * 4096 + r * 32 + lk];
    }
#pragma unroll
    for (int j = 0; j < 4; ++j) {
      int r = wn + j * 16 + lrow;
      short8 bh = *(const short8*)&lds[2 * 4096 + r * 32 + lk];
      short8 bl = *(const short8*)&lds[3 * 4096 + r * 32 + lk];
#pragma unroll
      for (int i = 0; i < 4; ++i) {
        acc[i][j] = __builtin_amdgcn_mfma_f32_16x16x32_bf16(ah[i], bh, acc[i][j], 0, 0, 0);
        acc[i][j] = __builtin_amdgcn_mfma_f32_16x16x32_bf16(ah[i], bl, acc[i][j], 0, 0, 0);
        acc[i][j] = __builtin_amdgcn_mfma_f32_16x16x32_bf16(al[i], bh, acc[i][j], 0, 0, 0);
      }
    }
    __syncthreads();
  }
#pragma unroll
  for (int i = 0; i < 4; ++i)
#pragma unroll
    for (int r = 0; r < 4; ++r) {
      int m = row0 + wm + i * 16 + ((l >> 4) << 2) + r;
      size_t base = (size_t)m * N;
#pragma unroll
      for (int j = 0; j < 4; ++j) {
        int n = col0 + wn + j * 16 + (l & 15);
        float v = acc[i][j][r];
        if (EPI == 0) {
          out16[base + n] = f2h(v);
        } else {
          out32[base + n] = v;
        }
      }
    }
}

// ---------------- fp32 recon GEMM (one-time; proven r3) ----------------
#define BM 128
#define BN 128
#define BKK 16

__global__ __launch_bounds__(256) void k_recon_f32(const float* __restrict__ A,
                                                   const float* __restrict__ Bm,
                                                   float* __restrict__ C, int M, int N, int Kd) {
  __shared__ float As[BKK][BM + 4];
  __shared__ float Bs[BKK][BN + 4];
  int tx = threadIdx.x & 15, ty = threadIdx.x >> 4;
  int row0 = blockIdx.y * BM, col0 = blockIdx.x * BN;
  float acc[8][8] = {};
  for (int k0 = 0; k0 < Kd; k0 += BKK) {
#pragma unroll
    for (int i = 0; i < 2; ++i) {
      int f = threadIdx.x + 256 * i;
      int r = f >> 2, kk = (f & 3) << 2;
      float4 a = *(const float4*)&A[(size_t)(row0 + r) * Kd + k0 + kk];
      As[kk + 0][r] = a.x; As[kk + 1][r] = a.y; As[kk + 2][r] = a.z; As[kk + 3][r] = a.w;
      int kr = f >> 5, nc = (f & 31) << 2;
      *(float4*)&Bs[kr][nc] = *(const float4*)&Bm[(size_t)(k0 + kr) * N + col0 + nc];
    }
    __syncthreads();
#pragma unroll
    for (int k = 0; k < BKK; ++k) {
      float a[8], b[8];
      *(float4*)&a[0] = *(const float4*)&As[k][ty * 8];
      *(float4*)&a[4] = *(const float4*)&As[k][ty * 8 + 4];
      *(float4*)&b[0] = *(const float4*)&Bs[k][tx * 8];
      *(float4*)&b[4] = *(const float4*)&Bs[k][tx * 8 + 4];
#pragma unroll
      for (int i = 0; i < 8; ++i)
#pragma unroll
        for (int j = 0; j < 8; ++j) acc[i][j] = fmaf(a[i], b[j], acc[i][j]);
    }
    __syncthreads();
  }
  int m0 = row0 + ty * 8, n0 = col0 + tx * 8;
#pragma unroll
  for (int i = 0; i < 8; ++i)
#pragma unroll
    for (int j4 = 0; j4 < 2; ++j4) {
      float4 c;
      c.x = acc[i][j4 * 4 + 0]; c.y = acc[i][j4 * 4 + 1];
      c.z = acc[i][j4 * 4 + 2]; c.w = acc[i][j4 * 4 + 3];
      *(float4*)&C[(size_t)(m0 + i) * N + n0 + j4 * 4] = c;
    }
}

// ---------------- fully-fused FISTA (ONE cooperative launch, 100 iterations) ----------------
// Per iteration: GEMM (r16-proven fp16 1-term, stage-first 1-tile-ahead,
// T1 remap + T2 swizzle + T5 setprio) -> grid.sync -> lean epilogue
// (fp16 alpha history, fp16 Cx; fp32 alpha written only at it==99)
// -> grid.sync (replaces the former kernel boundary; same fence semantics).

__device__ __forceinline__ void stage_op(const u16* src, int r0, int q0,
                                         u16* ldsbase, int tid) {
#pragma unroll
  for (int i = 0; i < 4; ++i) {
    int c = i * 512 + tid;
    int r = c >> 3;
    int sp = (c & 7) ^ (r & 7);
    const u16* gp = src + ((size_t)(r0 + r) << 11) + (q0 + (sp << 3));
    u16* lp = ldsbase + ((i * 512 + (tid & 448)) << 3);  // wave-uniform base
    __builtin_amdgcn_global_load_lds((const __attribute__((address_space(1))) void*)gp,
                                     (__attribute__((address_space(3))) void*)lp, 16, 0, 0);
  }
}

__global__ __launch_bounds__(512, 1) void k_fista_all(
    u16* Yh, u16* Af16,
    const u16* __restrict__ Gh,
    const u16* __restrict__ Cx, float* AlphaOut,
    const float* __restrict__ stepbuf, const float* __restrict__ mus) {
  __shared__ u16 lds[65536];  // 128 KB static: [buf][A 16384 u16 | B 16384 u16]
  cg::grid_group grid = cg::this_grid();

  const int tid = threadIdx.x;
  const int w = tid >> 6, l = tid & 63;
  const int wm = w >> 2, wn = w & 3;       // 2 x 4 waves
  const int lr = l & 15, lg = l >> 4;

  // XCD-aware remap (r9-verified: FETCH 595->332 MB/iter).
  const int lin = blockIdx.x + (int)gridDim.x * blockIdx.y;  // [0,256)
  const int bq = lin >> 6;          // [0,4)
  const int bp = (lin >> 3) & 7;    // [0,8)
  const int br = lin & 7;           // [0,8)
  const int row0 = ((bq << 3) + br) * 256;  // by = 8q + r
  const int col0 = bp * 256;                // bx = p

  const float step = stepbuf[0];
  const float thr = LAM * step;

  for (int it = 0; it < N_ITER; ++it) {
    const float mu = mus[it];
    f32x4 acc[8][4];
    f32x4 zero4 = {0.f, 0.f, 0.f, 0.f};
#pragma unroll
    for (int i = 0; i < 8; ++i)
#pragma unroll
      for (int j = 0; j < 4; ++j) acc[i][j] = zero4;

    // prologue: stage tile 0 into buf0 (overwrites last iter's stale wrap-stage,
    // which fully drained at the pre-sync vmcnt(0))
    stage_op(Yh, row0, 0, lds, tid);
    stage_op(Gh, col0, 0, lds + 16384, tid);

#define FBODY(TT, B)                                                              \
  {                                                                               \
    asm volatile("s_waitcnt vmcnt(0)" ::: "memory");                              \
    __builtin_amdgcn_s_barrier();                                                 \
    __builtin_amdgcn_sched_barrier(0);                                            \
    {                                                                             \
      int tn = (TT) + 1;                                                          \
      if (tn >= NTILES) tn = 0;                                                   \
      int q0 = tn << 6;                                                           \
      stage_op(Yh, row0, q0, lds + ((B) ? 0 : 32768), tid);                       \
      stage_op(Gh, col0, q0, lds + ((B) ? 0 : 32768) + 16384, tid);               \
    }                                                                             \
    __builtin_amdgcn_sched_barrier(0);                                            \
    const u16* baseA = lds + ((B) ? 32768 : 0);                                   \
    const u16* baseB = baseA + 16384;                                             \
    short8 bf[4][2];                                                              \
    _Pragma("unroll") for (int j = 0; j < 4; ++j) {                               \
      _Pragma("unroll") for (int ks = 0; ks < 2; ++ks) {                          \
        int brow = wn * 64 + j * 16 + lr;                                         \
        int slot = ks * 4 + lg;                                                   \
        bf[j][ks] = *(const short8*)(baseB + brow * 64 + ((slot ^ (brow & 7)) << 3)); \
      }                                                                           \
    }                                                                             \
    __builtin_amdgcn_s_setprio(1);                                                \
    _Pragma("unroll") for (int i = 0; i < 8; ++i) {                               \
      int arow = wm * 128 + i * 16 + lr;                                          \
      short8 a0 = *(const short8*)(baseA + arow * 64 + (((0 + lg) ^ (arow & 7)) << 3)); \
      short8 a1 = *(const short8*)(baseA + arow * 64 + (((4 + lg) ^ (arow & 7)) << 3)); \
      _Pragma("unroll") for (int j = 0; j < 4; ++j) {                             \
        acc[i][j] = __builtin_amdgcn_mfma_f32_16x16x32_f16(a0, bf[j][0], acc[i][j], 0, 0, 0); \
        acc[i][j] = __builtin_amdgcn_mfma_f32_16x16x32_f16(a1, bf[j][1], acc[i][j], 0, 0, 0); \
      }                                                                           \
    }                                                                             \
    __builtin_amdgcn_s_setprio(0);                                                \
  }

    for (int tt = 0; tt < NTILES; tt += 2) {
      FBODY(tt, 0)
      FBODY(tt + 1, 1)
    }
#undef FBODY

    asm volatile("s_waitcnt vmcnt(0)" ::: "memory");
    grid.sync();

    // ---- fused FISTA epilogue: each block updates only its own C-tile ----
#pragma unroll
    for (int i = 0; i < 8; ++i) {
#pragma unroll
      for (int r = 0; r < 4; ++r) {
        int m = row0 + wm * 128 + i * 16 + (lg << 2) + r;
        size_t base = (size_t)m * KB;
#pragma unroll
        for (int j = 0; j < 4; ++j) {
          int n = col0 + wn * 64 + j * 16 + lr;
          size_t idx = base + n;
          float g = acc[i][j][r] - h2f(Cx[idx]);
          float y = h2f(Yh[idx]);
          float z = y - step * g;
          float az = fabsf(z) - thr;
          float a = az > 0.f ? copysignf(az, z) : 0.f;
          float ap = h2f(Af16[idx]);
          float yn = a + mu * (a - ap);
          Af16[idx] = f2h(a);
          if (it == N_ITER - 1) AlphaOut[idx] = a;
          Yh[idx] = f2h(yn);
        }
      }
    }
    grid.sync();  // replaces former kernel boundary: epi writes -> next GEMM reads
  }
}

// ---------------- launch ----------------
extern "C" void kernel_launch(void* const* d_in, const int* in_sizes, int n_in,
                              void* d_out, int out_size, void* d_ws, size_t ws_size,
                              hipStream_t stream) {
  const float* x = (const float*)d_in[0];    // [8192,1024]
  const float* phi = (const float*)d_in[1];  // [2048,1024]
  float* out = (float*)d_out;
  float* alpha = out;                             // [8192*2048] fp32, written at last iter
  float* reconF = out + (size_t)BATCH * KB;       // [8192*1024] fp32 (33.55 MB scratch region)

  // ---- workspace layout (byte offsets) ----
  char* ws = (char*)d_ws;
  u16* Yh = (u16*)ws;                                   // 33,554,432 B (fp16 y)
  u16* Af16 = (u16*)(ws + 33554432ull);                 // 33,554,432 B (fp16 alpha history)
  u16* Gph = (u16*)(ws + 67108864ull);                  // 8,388,608 B  (Gh fp16; temp phiH bf16)
  u16* Gpl = (u16*)(ws + 75497472ull);                  // 8,388,608 B  (temp phiL bf16)
  u16* Cx16 = (u16*)(ws + 83886080ull);                 // 33,554,432 B (fp16 Cx)
  float* Gf = (float*)(ws + 117440512ull);              // 16,777,216 B (fp32 G for power iter)
  float* stepbuf = (float*)(ws + 150994944ull);         // 64 B
  float* musbuf = (float*)(ws + 150995008ull);          // 400 B
  const size_t need = 150995456ull;
  if (ws_size < need) return;

  // pre-FISTA temporaries in recon region of d_out:
  u16* xh = (u16*)reconF;           // x split hi [8192*1024]
  u16* xl = xh + (size_t)BATCH * DD;
  float* vbuf = reconF;             // power-iter scratch (xh/xl dead after Cx)
  float* partial = reconF + 4096;   // 64 floats

  // 1. splits: phi -> (Gph,Gpl temp, bf16 pair), x -> (xh,xl)
  k_split_f32<<<2048, 256, 0, stream>>>(phi, Gph, Gpl, KB * DD);
  k_split_f32<<<2048, 256, 0, stream>>>(x, xh, xl, BATCH * DD);

  // 2. Cx = x @ phi^T (fp16 out), M=8192 N=2048 K=1024
  k_xphiT<0><<<dim3(KB / 128, BATCH / 128), 256, 0, stream>>>(
      xh, xl, Gph, Gpl, Cx16, nullptr, KB, DD);

  // 3. G = phi @ phi^T (fp32 out via MFMA), M=N=2048 K=1024
  k_xphiT<1><<<dim3(KB / 128, KB / 128), 256, 0, stream>>>(
      Gph, Gpl, Gph, Gpl, nullptr, Gf, KB, DD);

  // 4. fused power iteration -> step, mu schedule (ONE cooperative launch)
  {
    const float* pG = Gf;
    float* pV = vbuf;
    float* pP = partial;
    float* pS = stepbuf;
    float* pM = musbuf;
    void* kargs[5] = {&pG, &pV, &pP, &pS, &pM};
    (void)hipLaunchCooperativeKernel((const void*)k_power_all, dim3(64),
                                     dim3(256), kargs, 0, stream);
  }

  // 5. Gh = fp16(G) (overwrites phiH split; dead after steps 2-3)
  k_cvt_f16<<<2048, 256, 0, stream>>>(Gf, Gph, KB * KB);

  // 6. zero Yh and Af16
  k_zero2<<<2048, 256, 0, stream>>>((float4*)Yh, (int)(33554432 / 16),
                                    (float4*)Af16, (int)(33554432 / 16));

  // 7. FISTA: ONE cooperative launch, 100 iterations inside
  {
    u16 *pYh = Yh, *pAf = Af16;
    const u16* pGh = Gph;
    const u16* pCx = Cx16;
    float* pAl = alpha;
    const float* pS = stepbuf;
    const float* pM = musbuf;
    void* kargs[7] = {&pYh, &pAf, &pGh, &pCx, &pAl, &pS, &pM};
    (void)hipLaunchCooperativeKernel((const void*)k_fista_all, dim3(KB / 256, BATCH / 256),
                                     dim3(512), kargs, 0, stream);
  }

  // 8. recon = alpha @ phi (fp32; overwrites recon-region scratch)
  k_recon_f32<<<dim3(DD / BN, BATCH / BM), 256, 0, stream>>>(
      alpha, phi, reconF, BATCH, DD, KB);
}

// Round 19
// 15003.740 us; speedup vs baseline: 1.9837x; 1.9837x over previous
//
#include <hip/hip_runtime.h>
#include <hip/hip_cooperative_groups.h>
#include <math.h>

namespace cg = cooperative_groups;

#define BATCH 8192
#define KB 2048      // num basis (N of fused GEMM)
#define DD 1024      // dim basis
#define LAM 0.1f
#define N_ITER 100
#define N_POWER 50
#define NTILES 32    // K' = 2048 = 32 * 64  (fp16 1-term: yh vs Gh)

typedef unsigned short u16;
using short8 = __attribute__((ext_vector_type(8))) short;
using f32x4  = __attribute__((ext_vector_type(4))) float;

// ---------- bf16 split helpers (RNE) ----------
__device__ __forceinline__ u16 f2bf(float f) {
  unsigned int u = __builtin_bit_cast(unsigned int, f);
  u = u + 0x7FFFu + ((u >> 16) & 1u);
  return (u16)(u >> 16);
}
__device__ __forceinline__ float bf2f(u16 s) {
  unsigned int u = ((unsigned int)s) << 16;
  return __builtin_bit_cast(float, u);
}

// ---------- fp16 helpers (RNE via HW cvt) ----------
__device__ __forceinline__ u16 f2h(float f) {
  _Float16 h = (_Float16)f;
  return __builtin_bit_cast(unsigned short, h);
}
__device__ __forceinline__ float h2f(u16 s) {
  _Float16 h = __builtin_bit_cast(_Float16, s);
  return (float)h;
}

// ---------------- utility kernels ----------------
__global__ void k_split_f32(const float* __restrict__ in, u16* __restrict__ h,
                            u16* __restrict__ lo, int n) {  // bf16 pair
  for (int i = blockIdx.x * blockDim.x + threadIdx.x; i < n; i += gridDim.x * blockDim.x) {
    float v = in[i];
    u16 hh = f2bf(v);
    h[i] = hh;
    lo[i] = f2bf(v - bf2f(hh));
  }
}

__global__ void k_cvt_f16(const float* __restrict__ in, u16* __restrict__ h, int n) {
  for (int i = blockIdx.x * blockDim.x + threadIdx.x; i < n; i += gridDim.x * blockDim.x)
    h[i] = f2h(in[i]);
}

__global__ void k_zero2(float4* __restrict__ a, int na, float4* __restrict__ b, int nb) {
  float4 z = {0.f, 0.f, 0.f, 0.f};
  for (int i = blockIdx.x * blockDim.x + threadIdx.x; i < na; i += gridDim.x * blockDim.x)
    a[i] = z;
  for (int i = blockIdx.x * blockDim.x + threadIdx.x; i < nb; i += gridDim.x * blockDim.x)
    b[i] = z;
}

// ---------------- fused power iteration (ONE cooperative launch; r18-proven) ----------------
// 64 blocks x 256 thr; arithmetic-identical to the multi-launch version
// (r18 ran it and absmax was unchanged at 0.09375). Tail computes step=1/L.
__global__ __launch_bounds__(256) void k_power_all(const float* __restrict__ G,
                                                   float* __restrict__ v,
                                                   float* __restrict__ partial,
                                                   float* __restrict__ stepbuf) {
  cg::grid_group grid = cg::this_grid();
  const int rloc = threadIdx.x >> 3;
  const int seg = threadIdx.x & 7;
  const int row = blockIdx.x * 32 + rloc;
  const int lane = threadIdx.x & 63, wid = threadIdx.x >> 6;
  __shared__ float red[4];

  if (seg == 0) v[row] = 1.f;
  grid.sync();

  for (int st = 0; st < N_POWER + 1; ++st) {
    const float* g = G + (size_t)row * KB + seg * 256;
    const float* vv = v + seg * 256;
    float s = 0.f;
#pragma unroll 8
    for (int j = 0; j < 256; j += 4) {
      float4 gg = *(const float4*)(g + j);
      float4 vx = *(const float4*)(vv + j);
      s = fmaf(gg.x, vx.x, fmaf(gg.y, vx.y, fmaf(gg.z, vx.z, fmaf(gg.w, vx.w, s))));
    }
#pragma unroll
    for (int off = 1; off < 8; off <<= 1) s += __shfl_xor(s, off, 64);
    float val;
    if (st < N_POWER)
      val = (seg == 0) ? s * s : 0.f;          // ||Gv||^2 partial
    else
      val = (seg == 0) ? v[row] * s : 0.f;     // Rayleigh numerator partial
#pragma unroll
    for (int off = 8; off < 64; off <<= 1) val += __shfl_xor(val, off, 64);
    if (lane == 0) red[wid] = val;
    __syncthreads();
    if (threadIdx.x == 0) partial[blockIdx.x] = red[0] + red[1] + red[2] + red[3];
    __syncthreads();
    grid.sync();

    if (st < N_POWER) {
      float n2 = 0.f;
#pragma unroll
      for (int i = 0; i < 64; ++i) n2 += partial[i];
      if (seg == 0) v[row] = s / sqrtf(n2);
      grid.sync();
    } else {
      if (blockIdx.x == 0 && threadIdx.x == 0) {
        float L = 0.f;
#pragma unroll
        for (int i = 0; i < 64; ++i) L += partial[i];
        stepbuf[0] = 1.f / L;
      }
    }
  }
}

// ---------------- split-bf16 MFMA GEMM: C = A @ B^T (r3-proven body) ----------------
// EPI 0: out16[m*N+n] = fp16(acc)   (Cx)
// EPI 1: out32[m*N+n] = acc         (Gram, fp32 for power iteration)
template <int EPI>
__global__ __launch_bounds__(256) void k_xphiT(
    const u16* __restrict__ Ah, const u16* __restrict__ Al,
    const u16* __restrict__ Bh, const u16* __restrict__ Bl,
    u16* __restrict__ out16, float* __restrict__ out32, int N, int K) {
  __shared__ u16 lds[4 * 128 * 32];
  const int tid = threadIdx.x;
  const int w = tid >> 6, l = tid & 63;
  const int row0 = blockIdx.y * 128, col0 = blockIdx.x * 128;
  const int wm = (w >> 1) * 64, wn = (w & 1) * 64;
  const int lrow = l & 15, lk = (l >> 4) * 8;

  f32x4 zero4 = {0.f, 0.f, 0.f, 0.f};
  f32x4 acc[4][4];
#pragma unroll
  for (int i = 0; i < 4; ++i)
#pragma unroll
    for (int j = 0; j < 4; ++j) acc[i][j] = zero4;

  for (int k0 = 0; k0 < K; k0 += 32) {
    {
      const u16* gs[4] = {Ah, Al, Bh, Bl};
      const int r0s[4] = {row0, row0, col0, col0};
#pragma unroll
      for (int st = 0; st < 4; ++st) {
        u16* s = lds + st * 4096;
#pragma unroll
        for (int h = 0; h < 2; ++h) {
          int ch = h * 256 + w * 64 + l;
          const u16* gp = gs[st] + (size_t)(r0s[st] + (ch >> 2)) * K + k0 + (ch & 3) * 8;
          u16* sp = s + (h * 256 + w * 64) * 8;
          __builtin_amdgcn_global_load_lds((const __attribute__((address_space(1))) void*)gp,
                                           (__attribute__((address_space(3))) void*)sp, 16, 0, 0);
        }
      }
    }
    __syncthreads();
    short8 ah[4], al[4];
#pragma unroll
    for (int i = 0; i < 4; ++i) {
      int r = wm + i * 16 + lrow;
      ah[i] = *(const short8*)&lds[0 * 4096 + r * 32 + lk];
      al[i] = *(const short8*)&lds[1 * 4096 + r * 32 + lk];
    }
#pragma unroll
    for (int j = 0; j < 4; ++j) {
      int r = wn + j * 16 + lrow;
      short8 bh = *(const short8*)&lds[2 * 4096 + r * 32 + lk];
      short8 bl = *(const short8*)&lds[3 * 4096 + r * 32 + lk];
#pragma unroll
      for (int i = 0; i < 4; ++i) {
        acc[i][j] = __builtin_amdgcn_mfma_f32_16x16x32_bf16(ah[i], bh, acc[i][j], 0, 0, 0);
        acc[i][j] = __builtin_amdgcn_mfma_f32_16x16x32_bf16(ah[i], bl, acc[i][j], 0, 0, 0);
        acc[i][j] = __builtin_amdgcn_mfma_f32_16x16x32_bf16(al[i], bh, acc[i][j], 0, 0, 0);
      }
    }
    __syncthreads();
  }
#pragma unroll
  for (int i = 0; i < 4; ++i)
#pragma unroll
    for (int r = 0; r < 4; ++r) {
      int m = row0 + wm + i * 16 + ((l >> 4) << 2) + r;
      size_t base = (size_t)m * N;
#pragma unroll
      for (int j = 0; j < 4; ++j) {
        int n = col0 + wn + j * 16 + (l & 15);
        float v = acc[i][j][r];
        if (EPI == 0) {
          out16[base + n] = f2h(v);
        } else {
          out32[base + n] = v;
        }
      }
    }
}

// ---------------- fp32 recon GEMM (one-time; proven r3) ----------------
#define BM 128
#define BN 128
#define BKK 16

__global__ __launch_bounds__(256) void k_recon_f32(const float* __restrict__ A,
                                                   const float* __restrict__ Bm,
                                                   float* __restrict__ C, int M, int N, int Kd) {
  __shared__ float As[BKK][BM + 4];
  __shared__ float Bs[BKK][BN + 4];
  int tx = threadIdx.x & 15, ty = threadIdx.x >> 4;
  int row0 = blockIdx.y * BM, col0 = blockIdx.x * BN;
  float acc[8][8] = {};
  for (int k0 = 0; k0 < Kd; k0 += BKK) {
#pragma unroll
    for (int i = 0; i < 2; ++i) {
      int f = threadIdx.x + 256 * i;
      int r = f >> 2, kk = (f & 3) << 2;
      float4 a = *(const float4*)&A[(size_t)(row0 + r) * Kd + k0 + kk];
      As[kk + 0][r] = a.x; As[kk + 1][r] = a.y; As[kk + 2][r] = a.z; As[kk + 3][r] = a.w;
      int kr = f >> 5, nc = (f & 31) << 2;
      *(float4*)&Bs[kr][nc] = *(const float4*)&Bm[(size_t)(k0 + kr) * N + col0 + nc];
    }
    __syncthreads();
#pragma unroll
    for (int k = 0; k < BKK; ++k) {
      float a[8], b[8];
      *(float4*)&a[0] = *(const float4*)&As[k][ty * 8];
      *(float4*)&a[4] = *(const float4*)&As[k][ty * 8 + 4];
      *(float4*)&b[0] = *(const float4*)&Bs[k][tx * 8];
      *(float4*)&b[4] = *(const float4*)&Bs[k][tx * 8 + 4];
#pragma unroll
      for (int i = 0; i < 8; ++i)
#pragma unroll
        for (int j = 0; j < 8; ++j) acc[i][j] = fmaf(a[i], b[j], acc[i][j]);
    }
    __syncthreads();
  }
  int m0 = row0 + ty * 8, n0 = col0 + tx * 8;
#pragma unroll
  for (int i = 0; i < 8; ++i)
#pragma unroll
    for (int j4 = 0; j4 < 2; ++j4) {
      float4 c;
      c.x = acc[i][j4 * 4 + 0]; c.y = acc[i][j4 * 4 + 1];
      c.z = acc[i][j4 * 4 + 2]; c.w = acc[i][j4 * 4 + 3];
      *(float4*)&C[(size_t)(m0 + i) * N + n0 + j4 * 4] = c;
    }
}

// ---------------- fused FISTA iteration (cooperative; r17-proven 14.44ms) ----------------
// One launch per iteration (r18 proved persistent+200 grid.syncs is 2x WORSE:
// kernel boundaries are the cheap device-wide sync on this chip).

__device__ __forceinline__ void stage_op(const u16* src, int r0, int q0,
                                         u16* ldsbase, int tid) {
#pragma unroll
  for (int i = 0; i < 4; ++i) {
    int c = i * 512 + tid;
    int r = c >> 3;
    int sp = (c & 7) ^ (r & 7);
    const u16* gp = src + ((size_t)(r0 + r) << 11) + (q0 + (sp << 3));
    u16* lp = ldsbase + ((i * 512 + (tid & 448)) << 3);  // wave-uniform base
    __builtin_amdgcn_global_load_lds((const __attribute__((address_space(1))) void*)gp,
                                     (__attribute__((address_space(3))) void*)lp, 16, 0, 0);
  }
}

__global__ __launch_bounds__(512, 1) void k_fista_fused(
    u16* Yh, u16* Af16,
    const u16* __restrict__ Gh,
    const u16* __restrict__ Cx, float* AlphaOut,
    const float* __restrict__ stepbuf, float mu, int last) {
  __shared__ u16 lds[65536];  // 128 KB static: [buf][A 16384 u16 | B 16384 u16]

  const int tid = threadIdx.x;
  const int w = tid >> 6, l = tid & 63;
  const int wm = w >> 2, wn = w & 3;       // 2 x 4 waves
  const int lr = l & 15, lg = l >> 4;

  // XCD-aware remap (r9-verified: FETCH 595->332 MB/iter).
  const int lin = blockIdx.x + (int)gridDim.x * blockIdx.y;  // [0,256)
  const int bq = lin >> 6;          // [0,4)
  const int bp = (lin >> 3) & 7;    // [0,8)
  const int br = lin & 7;           // [0,8)
  const int row0 = ((bq << 3) + br) * 256;  // by = 8q + r
  const int col0 = bp * 256;                // bx = p

  f32x4 acc[8][4];
  f32x4 zero4 = {0.f, 0.f, 0.f, 0.f};
#pragma unroll
  for (int i = 0; i < 8; ++i)
#pragma unroll
    for (int j = 0; j < 4; ++j) acc[i][j] = zero4;

  // prologue: stage tile 0 into buf0 only (1-tile-ahead scheme)
  stage_op(Yh, row0, 0, lds, tid);
  stage_op(Gh, col0, 0, lds + 16384, tid);

#define FBODY(TT, B)                                                              \
  {                                                                               \
    asm volatile("s_waitcnt vmcnt(0)" ::: "memory");                              \
    __builtin_amdgcn_s_barrier();                                                 \
    __builtin_amdgcn_sched_barrier(0);                                            \
    {                                                                             \
      int tn = (TT) + 1;                                                          \
      if (tn >= NTILES) tn = 0;                                                   \
      int q0 = tn << 6;                                                           \
      stage_op(Yh, row0, q0, lds + ((B) ? 0 : 32768), tid);                       \
      stage_op(Gh, col0, q0, lds + ((B) ? 0 : 32768) + 16384, tid);               \
    }                                                                             \
    __builtin_amdgcn_sched_barrier(0);                                            \
    const u16* baseA = lds + ((B) ? 32768 : 0);                                   \
    const u16* baseB = baseA + 16384;                                             \
    short8 bf[4][2];                                                              \
    _Pragma("unroll") for (int j = 0; j < 4; ++j) {                               \
      _Pragma("unroll") for (int ks = 0; ks < 2; ++ks) {                          \
        int brow = wn * 64 + j * 16 + lr;                                         \
        int slot = ks * 4 + lg;                                                   \
        bf[j][ks] = *(const short8*)(baseB + brow * 64 + ((slot ^ (brow & 7)) << 3)); \
      }                                                                           \
    }                                                                             \
    __builtin_amdgcn_s_setprio(1);                                                \
    _Pragma("unroll") for (int i = 0; i < 8; ++i) {                               \
      int arow = wm * 128 + i * 16 + lr;                                          \
      short8 a0 = *(const short8*)(baseA + arow * 64 + (((0 + lg) ^ (arow & 7)) << 3)); \
      short8 a1 = *(const short8*)(baseA + arow * 64 + (((4 + lg) ^ (arow & 7)) << 3)); \
      _Pragma("unroll") for (int j = 0; j < 4; ++j) {                             \
        acc[i][j] = __builtin_amdgcn_mfma_f32_16x16x32_f16(a0, bf[j][0], acc[i][j], 0, 0, 0); \
        acc[i][j] = __builtin_amdgcn_mfma_f32_16x16x32_f16(a1, bf[j][1], acc[i][j], 0, 0, 0); \
      }                                                                           \
    }                                                                             \
    __builtin_amdgcn_s_setprio(0);                                                \
  }

  for (int tt = 0; tt < NTILES; tt += 2) {
    FBODY(tt, 0)
    FBODY(tt + 1, 1)
  }
#undef FBODY

  asm volatile("s_waitcnt vmcnt(0)" ::: "memory");
  cg::this_grid().sync();

  // ---- fused FISTA epilogue: each block updates only its own C-tile ----
  const float step = stepbuf[0];
  const float thr = LAM * step;
#pragma unroll
  for (int i = 0; i < 8; ++i) {
#pragma unroll
    for (int r = 0; r < 4; ++r) {
      int m = row0 + wm * 128 + i * 16 + (lg << 2) + r;
      size_t base = (size_t)m * KB;
#pragma unroll
      for (int j = 0; j < 4; ++j) {
        int n = col0 + wn * 64 + j * 16 + lr;
        size_t idx = base + n;
        float g = acc[i][j][r] - h2f(Cx[idx]);
        float y = h2f(Yh[idx]);
        float z = y - step * g;
        float az = fabsf(z) - thr;
        float a = az > 0.f ? copysignf(az, z) : 0.f;
        float ap = h2f(Af16[idx]);
        float yn = a + mu * (a - ap);
        Af16[idx] = f2h(a);
        if (last) AlphaOut[idx] = a;
        Yh[idx] = f2h(yn);
      }
    }
  }
}

// ---------------- launch ----------------
extern "C" void kernel_launch(void* const* d_in, const int* in_sizes, int n_in,
                              void* d_out, int out_size, void* d_ws, size_t ws_size,
                              hipStream_t stream) {
  const float* x = (const float*)d_in[0];    // [8192,1024]
  const float* phi = (const float*)d_in[1];  // [2048,1024]
  float* out = (float*)d_out;
  float* alpha = out;                             // [8192*2048] fp32, written at last iter
  float* reconF = out + (size_t)BATCH * KB;       // [8192*1024] fp32 (33.55 MB scratch region)

  // ---- workspace layout (byte offsets) ----
  char* ws = (char*)d_ws;
  u16* Yh = (u16*)ws;                                   // 33,554,432 B (fp16 y)
  u16* Af16 = (u16*)(ws + 33554432ull);                 // 33,554,432 B (fp16 alpha history)
  u16* Gph = (u16*)(ws + 67108864ull);                  // 8,388,608 B  (Gh fp16; temp phiH bf16)
  u16* Gpl = (u16*)(ws + 75497472ull);                  // 8,388,608 B  (temp phiL bf16)
  u16* Cx16 = (u16*)(ws + 83886080ull);                 // 33,554,432 B (fp16 Cx)
  float* Gf = (float*)(ws + 117440512ull);              // 16,777,216 B (fp32 G for power iter)
  float* stepbuf = (float*)(ws + 150994944ull);         // 64 B
  const size_t need = 150995008ull;
  if (ws_size < need) return;

  // pre-FISTA temporaries in recon region of d_out:
  u16* xh = (u16*)reconF;           // x split hi [8192*1024]
  u16* xl = xh + (size_t)BATCH * DD;
  float* vbuf = reconF;             // power-iter scratch (xh/xl dead after Cx)
  float* partial = reconF + 4096;   // 64 floats

  // 1. splits: phi -> (Gph,Gpl temp, bf16 pair), x -> (xh,xl)
  k_split_f32<<<2048, 256, 0, stream>>>(phi, Gph, Gpl, KB * DD);
  k_split_f32<<<2048, 256, 0, stream>>>(x, xh, xl, BATCH * DD);

  // 2. Cx = x @ phi^T (fp16 out), M=8192 N=2048 K=1024
  k_xphiT<0><<<dim3(KB / 128, BATCH / 128), 256, 0, stream>>>(
      xh, xl, Gph, Gpl, Cx16, nullptr, KB, DD);

  // 3. G = phi @ phi^T (fp32 out via MFMA), M=N=2048 K=1024
  k_xphiT<1><<<dim3(KB / 128, KB / 128), 256, 0, stream>>>(
      Gph, Gpl, Gph, Gpl, nullptr, Gf, KB, DD);

  // 4. fused power iteration -> step (ONE cooperative launch; r18-proven)
  {
    const float* pG = Gf;
    float* pV = vbuf;
    float* pP = partial;
    float* pS = stepbuf;
    void* kargs[4] = {&pG, &pV, &pP, &pS};
    (void)hipLaunchCooperativeKernel((const void*)k_power_all, dim3(64),
                                     dim3(256), kargs, 0, stream);
  }

  // 5. Gh = fp16(G) (overwrites phiH split; dead after steps 2-3)
  k_cvt_f16<<<2048, 256, 0, stream>>>(Gf, Gph, KB * KB);

  // 6. zero Yh and Af16
  k_zero2<<<2048, 256, 0, stream>>>((float4*)Yh, (int)(33554432 / 16),
                                    (float4*)Af16, (int)(33554432 / 16));

  // 7. FISTA: 100 cooperative fused iterations (r17-proven structure)
  float t = 1.f;
  float mus[N_ITER];
  int lasts[N_ITER];
  for (int it = 0; it < N_ITER; ++it) {
    float tn = 0.5f * (1.f + sqrtf(1.f + 4.f * t * t));
    mus[it] = (t - 1.f) / tn;
    lasts[it] = (it == N_ITER - 1) ? 1 : 0;
    t = tn;
  }
  u16 *pYh = Yh, *pAf = Af16;
  const u16* pGh = Gph;
  const u16* pCx = Cx16;
  float* pAl = alpha;
  const float* pStep = stepbuf;
  for (int it = 0; it < N_ITER; ++it) {
    void* kargs[8] = {&pYh, &pAf, &pGh, &pCx, &pAl, &pStep, &mus[it], &lasts[it]};
    (void)hipLaunchCooperativeKernel((const void*)k_fista_fused, dim3(KB / 256, BATCH / 256),
                                     dim3(512), kargs, 0, stream);
  }

  // 8. recon = alpha @ phi (fp32; overwrites recon-region scratch)
  k_recon_f32<<<dim3(DD / BN, BATCH / BM), 256, 0, stream>>>(
      alpha, phi, reconF, BATCH, DD, KB);
}

// Round 20
// 13888.406 us; speedup vs baseline: 2.1430x; 1.0803x over previous
//
#include <hip/hip_runtime.h>
#include <hip/hip_cooperative_groups.h>
#include <math.h>

namespace cg = cooperative_groups;

#define BATCH 8192
#define KB 2048      // num basis (N of fused GEMM)
#define DD 1024      // dim basis
#define LAM 0.1f
#define N_ITER 100
#define N_POWER 50
#define NTILES 32    // K' = 2048 = 32 * 64  (fp16 1-term: yh vs Gh)

typedef unsigned short u16;
using short8 = __attribute__((ext_vector_type(8))) short;
using f32x4  = __attribute__((ext_vector_type(4))) float;

// ---------- bf16 split helpers (RNE) ----------
__device__ __forceinline__ u16 f2bf(float f) {
  unsigned int u = __builtin_bit_cast(unsigned int, f);
  u = u + 0x7FFFu + ((u >> 16) & 1u);
  return (u16)(u >> 16);
}
__device__ __forceinline__ float bf2f(u16 s) {
  unsigned int u = ((unsigned int)s) << 16;
  return __builtin_bit_cast(float, u);
}

// ---------- fp16 helpers (RNE via HW cvt) ----------
__device__ __forceinline__ u16 f2h(float f) {
  _Float16 h = (_Float16)f;
  return __builtin_bit_cast(unsigned short, h);
}
__device__ __forceinline__ float h2f(u16 s) {
  _Float16 h = __builtin_bit_cast(_Float16, s);
  return (float)h;
}

// ---------------- utility kernels ----------------
__global__ void k_split_f32(const float* __restrict__ in, u16* __restrict__ h,
                            u16* __restrict__ lo, int n) {  // bf16 pair
  for (int i = blockIdx.x * blockDim.x + threadIdx.x; i < n; i += gridDim.x * blockDim.x) {
    float v = in[i];
    u16 hh = f2bf(v);
    h[i] = hh;
    lo[i] = f2bf(v - bf2f(hh));
  }
}

// transposed bf16-pair split: th/tl[d][k] = split(phi[k][d])  (r3-proven)
__global__ __launch_bounds__(256) void k_split_phiT(const float* __restrict__ phi,
                                                    u16* __restrict__ th, u16* __restrict__ tl) {
  __shared__ float t[32][33];
  int k0 = blockIdx.y * 32, d0 = blockIdx.x * 32;
  int tx = threadIdx.x & 31, ty = threadIdx.x >> 5;  // 8 rows per pass
#pragma unroll
  for (int rr = 0; rr < 32; rr += 8)
    t[ty + rr][tx] = phi[(size_t)(k0 + ty + rr) * DD + d0 + tx];
  __syncthreads();
#pragma unroll
  for (int rr = 0; rr < 32; rr += 8) {
    float v = t[tx][ty + rr];  // = phi[k0+tx][d0+ty+rr]
    u16 hh = f2bf(v);
    size_t idx = (size_t)(d0 + ty + rr) * KB + (k0 + tx);
    th[idx] = hh;
    tl[idx] = f2bf(v - bf2f(hh));
  }
}

__global__ void k_cvt_f16(const float* __restrict__ in, u16* __restrict__ h, int n) {
  for (int i = blockIdx.x * blockDim.x + threadIdx.x; i < n; i += gridDim.x * blockDim.x)
    h[i] = f2h(in[i]);
}

// init power iteration: w = ones, partialA = 1/64 each (sum = 1 -> first norm = 1)
__global__ void k_init_pw(float* __restrict__ w, float* __restrict__ pA) {
  int i = blockIdx.x * 256 + threadIdx.x;
  if (i < KB) w[i] = 1.f;
  if (i < 64) pA[i] = 1.f / 64.f;
}

// ---------------- fused power step (normalize folded into matvec) ----------------
// MODE 0: wout = (G @ win) / sqrt(sum(pin));  pout[b] = block-sum of wout^2
// MODE 1: pout[b] = block-sum of (win/n) * ((G @ win)/n)  (Rayleigh numerator)
// Ping-pong w and partial buffers between launches -> no intra-launch races,
// no grid.sync (r18/r19: software grid-sync costs ~2x a kernel boundary).
template <int MODE>
__global__ __launch_bounds__(256) void k_power_fused(const float* __restrict__ G,
                                                     const float* __restrict__ win,
                                                     float* __restrict__ wout,
                                                     const float* __restrict__ pin,
                                                     float* __restrict__ pout) {
  int rloc = threadIdx.x >> 3;
  int seg = threadIdx.x & 7;
  int row = blockIdx.x * 32 + rloc;
  float n2 = 0.f;
#pragma unroll
  for (int i = 0; i < 64; ++i) n2 += pin[i];
  float n = sqrtf(n2);
  const float* g = G + (size_t)row * KB + seg * 256;
  const float* vv = win + seg * 256;
  float s = 0.f;
#pragma unroll 8
  for (int j = 0; j < 256; j += 4) {
    float4 gg = *(const float4*)(g + j);
    float4 vx = *(const float4*)(vv + j);
    s = fmaf(gg.x, vx.x, fmaf(gg.y, vx.y, fmaf(gg.z, vx.z, fmaf(gg.w, vx.w, s))));
  }
#pragma unroll
  for (int off = 1; off < 8; off <<= 1) s += __shfl_xor(s, off, 64);
  s = s / n;  // = row of G @ (win/||win||)
  float val;
  if (MODE == 0) {
    if (seg == 0) wout[row] = s;
    val = (seg == 0) ? s * s : 0.f;
  } else {
    val = (seg == 0) ? (win[row] / n) * s : 0.f;
  }
#pragma unroll
  for (int off = 8; off < 64; off <<= 1) val += __shfl_xor(val, off, 64);
  __shared__ float red[4];
  int lane = threadIdx.x & 63, wid = threadIdx.x >> 6;
  if (lane == 0) red[wid] = val;
  __syncthreads();
  if (threadIdx.x == 0) pout[blockIdx.x] = red[0] + red[1] + red[2] + red[3];
}

__global__ void k_compute_step(const float* __restrict__ partialL, float* __restrict__ stepbuf) {
  float L = 0.f;
#pragma unroll
  for (int i = 0; i < 64; ++i) L += partialL[i];
  stepbuf[0] = 1.f / L;
}

// ---------------- split-bf16 MFMA GEMM: C = A @ B^T (r3-proven body) ----------------
// EPI 0: out16[m*N+n] = fp16(acc)   (Cx)
// EPI 1: out32[m*N+n] = acc         (Gram fp32; also recon fp32)
template <int EPI>
__global__ __launch_bounds__(256) void k_xphiT(
    const u16* __restrict__ Ah, const u16* __restrict__ Al,
    const u16* __restrict__ Bh, const u16* __restrict__ Bl,
    u16* __restrict__ out16, float* __restrict__ out32, int N, int K) {
  __shared__ u16 lds[4 * 128 * 32];
  const int tid = threadIdx.x;
  const int w = tid >> 6, l = tid & 63;
  const int row0 = blockIdx.y * 128, col0 = blockIdx.x * 128;
  const int wm = (w >> 1) * 64, wn = (w & 1) * 64;
  const int lrow = l & 15, lk = (l >> 4) * 8;

  f32x4 zero4 = {0.f, 0.f, 0.f, 0.f};
  f32x4 acc[4][4];
#pragma unroll
  for (int i = 0; i < 4; ++i)
#pragma unroll
    for (int j = 0; j < 4; ++j) acc[i][j] = zero4;

  for (int k0 = 0; k0 < K; k0 += 32) {
    {
      const u16* gs[4] = {Ah, Al, Bh, Bl};
      const int r0s[4] = {row0, row0, col0, col0};
#pragma unroll
      for (int st = 0; st < 4; ++st) {
        u16* s = lds + st * 4096;
#pragma unroll
        for (int h = 0; h < 2; ++h) {
          int ch = h * 256 + w * 64 + l;
          const u16* gp = gs[st] + (size_t)(r0s[st] + (ch >> 2)) * K + k0 + (ch & 3) * 8;
          u16* sp = s + (h * 256 + w * 64) * 8;
          __builtin_amdgcn_global_load_lds((const __attribute__((address_space(1))) void*)gp,
                                           (__attribute__((address_space(3))) void*)sp, 16, 0, 0);
        }
      }
    }
    __syncthreads();
    short8 ah[4], al[4];
#pragma unroll
    for (int i = 0; i < 4; ++i) {
      int r = wm + i * 16 + lrow;
      ah[i] = *(const short8*)&lds[0 * 4096 + r * 32 + lk];
      al[i] = *(const short8*)&lds[1 * 4096 + r * 32 + lk];
    }
#pragma unroll
    for (int j = 0; j < 4; ++j) {
      int r = wn + j * 16 + lrow;
      short8 bh = *(const short8*)&lds[2 * 4096 + r * 32 + lk];
      short8 bl = *(const short8*)&lds[3 * 4096 + r * 32 + lk];
#pragma unroll
      for (int i = 0; i < 4; ++i) {
        acc[i][j] = __builtin_amdgcn_mfma_f32_16x16x32_bf16(ah[i], bh, acc[i][j], 0, 0, 0);
        acc[i][j] = __builtin_amdgcn_mfma_f32_16x16x32_bf16(ah[i], bl, acc[i][j], 0, 0, 0);
        acc[i][j] = __builtin_amdgcn_mfma_f32_16x16x32_bf16(al[i], bh, acc[i][j], 0, 0, 0);
      }
    }
    __syncthreads();
  }
#pragma unroll
  for (int i = 0; i < 4; ++i)
#pragma unroll
    for (int r = 0; r < 4; ++r) {
      int m = row0 + wm + i * 16 + ((l >> 4) << 2) + r;
      size_t base = (size_t)m * N;
#pragma unroll
      for (int j = 0; j < 4; ++j) {
        int n = col0 + wn + j * 16 + (l & 15);
        float v = acc[i][j][r];
        if (EPI == 0) {
          out16[base + n] = f2h(v);
        } else {
          out32[base + n] = v;
        }
      }
    }
}

// ---------------- iteration 0 (closed form: y=alpha=0, mu0=0) ----------------
// a = soft(step*Cx, lam*step); Af16 = Yh = fp16(a). Replaces zero-init + one
// cooperative GEMM launch; arithmetic-identical to r17's it==0.
__global__ void k_iter0(const u16* __restrict__ Cx, u16* __restrict__ Yh,
                        u16* __restrict__ Af16, const float* __restrict__ stepbuf) {
  const float step = stepbuf[0];
  const float thr = LAM * step;
  int n = BATCH * KB;
  for (int i = blockIdx.x * blockDim.x + threadIdx.x; i < n; i += gridDim.x * blockDim.x) {
    float z = step * h2f(Cx[i]);
    float az = fabsf(z) - thr;
    float a = az > 0.f ? copysignf(az, z) : 0.f;
    u16 ah = f2h(a);
    Af16[i] = ah;
    Yh[i] = ah;
  }
}

// ---------------- fused FISTA iteration (cooperative; r17-proven) ----------------
__device__ __forceinline__ void stage_op(const u16* src, int r0, int q0,
                                         u16* ldsbase, int tid) {
#pragma unroll
  for (int i = 0; i < 4; ++i) {
    int c = i * 512 + tid;
    int r = c >> 3;
    int sp = (c & 7) ^ (r & 7);
    const u16* gp = src + ((size_t)(r0 + r) << 11) + (q0 + (sp << 3));
    u16* lp = ldsbase + ((i * 512 + (tid & 448)) << 3);  // wave-uniform base
    __builtin_amdgcn_global_load_lds((const __attribute__((address_space(1))) void*)gp,
                                     (__attribute__((address_space(3))) void*)lp, 16, 0, 0);
  }
}

__global__ __launch_bounds__(512, 1) void k_fista_fused(
    u16* Yh, u16* Af16,
    const u16* __restrict__ Gh,
    const u16* __restrict__ Cx, float* AlphaOut,
    const float* __restrict__ stepbuf, float mu, int last) {
  __shared__ u16 lds[65536];  // 128 KB static: [buf][A 16384 u16 | B 16384 u16]

  const int tid = threadIdx.x;
  const int w = tid >> 6, l = tid & 63;
  const int wm = w >> 2, wn = w & 3;       // 2 x 4 waves
  const int lr = l & 15, lg = l >> 4;

  // XCD-aware remap (r9-verified: FETCH 595->332 MB/iter).
  const int lin = blockIdx.x + (int)gridDim.x * blockIdx.y;  // [0,256)
  const int bq = lin >> 6;          // [0,4)
  const int bp = (lin >> 3) & 7;    // [0,8)
  const int br = lin & 7;           // [0,8)
  const int row0 = ((bq << 3) + br) * 256;  // by = 8q + r
  const int col0 = bp * 256;                // bx = p

  f32x4 acc[8][4];
  f32x4 zero4 = {0.f, 0.f, 0.f, 0.f};
#pragma unroll
  for (int i = 0; i < 8; ++i)
#pragma unroll
    for (int j = 0; j < 4; ++j) acc[i][j] = zero4;

  // prologue: stage tile 0 into buf0 only (1-tile-ahead scheme)
  stage_op(Yh, row0, 0, lds, tid);
  stage_op(Gh, col0, 0, lds + 16384, tid);

#define FBODY(TT, B)                                                              \
  {                                                                               \
    asm volatile("s_waitcnt vmcnt(0)" ::: "memory");                              \
    __builtin_amdgcn_s_barrier();                                                 \
    __builtin_amdgcn_sched_barrier(0);                                            \
    {                                                                             \
      int tn = (TT) + 1;                                                          \
      if (tn >= NTILES) tn = 0;                                                   \
      int q0 = tn << 6;                                                           \
      stage_op(Yh, row0, q0, lds + ((B) ? 0 : 32768), tid);                       \
      stage_op(Gh, col0, q0, lds + ((B) ? 0 : 32768) + 16384, tid);               \
    }                                                                             \
    __builtin_amdgcn_sched_barrier(0);                                            \
    const u16* baseA = lds + ((B) ? 32768 : 0);                                   \
    const u16* baseB = baseA + 16384;                                             \
    short8 bf[4][2];                                                              \
    _Pragma("unroll") for (int j = 0; j < 4; ++j) {                               \
      _Pragma("unroll") for (int ks = 0; ks < 2; ++ks) {                          \
        int brow = wn * 64 + j * 16 + lr;                                         \
        int slot = ks * 4 + lg;                                                   \
        bf[j][ks] = *(const short8*)(baseB + brow * 64 + ((slot ^ (brow & 7)) << 3)); \
      }                                                                           \
    }                                                                             \
    __builtin_amdgcn_s_setprio(1);                                                \
    _Pragma("unroll") for (int i = 0; i < 8; ++i) {                               \
      int arow = wm * 128 + i * 16 + lr;                                          \
      short8 a0 = *(const short8*)(baseA + arow * 64 + (((0 + lg) ^ (arow & 7)) << 3)); \
      short8 a1 = *(const short8*)(baseA + arow * 64 + (((4 + lg) ^ (arow & 7)) << 3)); \
      _Pragma("unroll") for (int j = 0; j < 4; ++j) {                             \
        acc[i][j] = __builtin_amdgcn_mfma_f32_16x16x32_f16(a0, bf[j][0], acc[i][j], 0, 0, 0); \
        acc[i][j] = __builtin_amdgcn_mfma_f32_16x16x32_f16(a1, bf[j][1], acc[i][j], 0, 0, 0); \
      }                                                                           \
    }                                                                             \
    __builtin_amdgcn_s_setprio(0);                                                \
  }

  for (int tt = 0; tt < NTILES; tt += 2) {
    FBODY(tt, 0)
    FBODY(tt + 1, 1)
  }
#undef FBODY

  asm volatile("s_waitcnt vmcnt(0)" ::: "memory");
  cg::this_grid().sync();

  // ---- fused FISTA epilogue: each block updates only its own C-tile ----
  const float step = stepbuf[0];
  const float thr = LAM * step;
#pragma unroll
  for (int i = 0; i < 8; ++i) {
#pragma unroll
    for (int r = 0; r < 4; ++r) {
      int m = row0 + wm * 128 + i * 16 + (lg << 2) + r;
      size_t base = (size_t)m * KB;
#pragma unroll
      for (int j = 0; j < 4; ++j) {
        int n = col0 + wn * 64 + j * 16 + lr;
        size_t idx = base + n;
        float g = acc[i][j][r] - h2f(Cx[idx]);
        float y = h2f(Yh[idx]);
        float z = y - step * g;
        float az = fabsf(z) - thr;
        float a = az > 0.f ? copysignf(az, z) : 0.f;
        float ap = h2f(Af16[idx]);
        float yn = a + mu * (a - ap);
        Af16[idx] = f2h(a);
        if (last) AlphaOut[idx] = a;
        Yh[idx] = f2h(yn);
      }
    }
  }
}

// ---------------- launch ----------------
extern "C" void kernel_launch(void* const* d_in, const int* in_sizes, int n_in,
                              void* d_out, int out_size, void* d_ws, size_t ws_size,
                              hipStream_t stream) {
  const float* x = (const float*)d_in[0];    // [8192,1024]
  const float* phi = (const float*)d_in[1];  // [2048,1024]
  float* out = (float*)d_out;
  float* alpha = out;                             // [8192*2048] fp32, written at last iter
  float* reconF = out + (size_t)BATCH * KB;       // [8192*1024] fp32 (33.55 MB scratch region)

  // ---- workspace layout (byte offsets) ----
  char* ws = (char*)d_ws;
  u16* Yh = (u16*)ws;                                   // 33,554,432 B (fp16 y; later alphaH bf16)
  u16* Af16 = (u16*)(ws + 33554432ull);                 // 33,554,432 B (fp16 alpha; later alphaL bf16)
  u16* Gph = (u16*)(ws + 67108864ull);                  // 8,388,608 B  (Gh fp16; temp phiH bf16)
  u16* Gpl = (u16*)(ws + 75497472ull);                  // 8,388,608 B  (temp phiL bf16)
  u16* Cx16 = (u16*)(ws + 83886080ull);                 // 33,554,432 B (fp16 Cx)
  float* Gf = (float*)(ws + 117440512ull);              // 16,777,216 B (fp32 G; later phiT splits)
  float* stepbuf = (float*)(ws + 150994944ull);         // 64 B
  const size_t need = 150995008ull;
  if (ws_size < need) return;

  // pre-FISTA temporaries in recon region of d_out:
  u16* xh = (u16*)reconF;           // x split hi [8192*1024]
  u16* xl = xh + (size_t)BATCH * DD;
  float* vA = reconF;               // power-iter ping-pong (xh/xl dead after Cx)
  float* vB = reconF + 2048;
  float* pA = reconF + 4096;        // 64 floats
  float* pB = reconF + 4224;        // 64 floats

  // 1. splits: phi -> (Gph,Gpl temp, bf16 pair), x -> (xh,xl)
  k_split_f32<<<2048, 256, 0, stream>>>(phi, Gph, Gpl, KB * DD);
  k_split_f32<<<2048, 256, 0, stream>>>(x, xh, xl, BATCH * DD);

  // 2. Cx = x @ phi^T (fp16 out), M=8192 N=2048 K=1024
  k_xphiT<0><<<dim3(KB / 128, BATCH / 128), 256, 0, stream>>>(
      xh, xl, Gph, Gpl, Cx16, nullptr, KB, DD);

  // 3. G = phi @ phi^T (fp32 out via MFMA), M=N=2048 K=1024
  k_xphiT<1><<<dim3(KB / 128, KB / 128), 256, 0, stream>>>(
      Gph, Gpl, Gph, Gpl, nullptr, Gf, KB, DD);

  // 4. power iteration: 50 fused steps (ping-pong) + Rayleigh + step
  k_init_pw<<<8, 256, 0, stream>>>(vA, pA);
  for (int s = 0; s < N_POWER; ++s) {
    const float* win = (s & 1) ? vB : vA;
    float* wout = (s & 1) ? vA : vB;
    const float* pin = (s & 1) ? pB : pA;
    float* pout = (s & 1) ? pA : pB;
    k_power_fused<0><<<64, 256, 0, stream>>>(Gf, win, wout, pin, pout);
  }
  // after 50 steps (even): w in vA, partials in pA
  k_power_fused<1><<<64, 256, 0, stream>>>(Gf, vA, nullptr, pA, pB);
  k_compute_step<<<1, 1, 0, stream>>>(pB, stepbuf);

  // 5. Gh = fp16(G) (overwrites phiH split; dead after steps 2-3)
  k_cvt_f16<<<2048, 256, 0, stream>>>(Gf, Gph, KB * KB);

  // 6. iteration 0 closed-form (replaces zero-init + first GEMM launch)
  k_iter0<<<2048, 256, 0, stream>>>(Cx16, Yh, Af16, stepbuf);

  // 7. FISTA iterations 1..99 (r17-proven per-iteration cooperative launches)
  float t = 1.f;
  float mus[N_ITER];
  int lasts[N_ITER];
  for (int it = 0; it < N_ITER; ++it) {
    float tn = 0.5f * (1.f + sqrtf(1.f + 4.f * t * t));
    mus[it] = (t - 1.f) / tn;
    lasts[it] = (it == N_ITER - 1) ? 1 : 0;
    t = tn;
  }
  u16 *pYh = Yh, *pAf = Af16;
  const u16* pGh = Gph;
  const u16* pCx = Cx16;
  float* pAl = alpha;
  const float* pStep = stepbuf;
  for (int it = 1; it < N_ITER; ++it) {
    void* kargs[8] = {&pYh, &pAf, &pGh, &pCx, &pAl, &pStep, &mus[it], &lasts[it]};
    (void)hipLaunchCooperativeKernel((const void*)k_fista_fused, dim3(KB / 256, BATCH / 256),
                                     dim3(512), kargs, 0, stream);
  }

  // 8. recon = alpha @ phi via split-bf16 MFMA (alpha splits into dead Yh/Af16;
  //    phi^T splits into dead Gf region; all three kernels r3-proven)
  u16* aH = Yh;                       // bf16 alpha hi
  u16* aL = Af16;                     // bf16 alpha lo
  u16* pTh = (u16*)Gf;                // bf16 phiT hi [DD][KB]
  u16* pTl = pTh + (size_t)DD * KB;   // bf16 phiT lo
  k_split_f32<<<2048, 256, 0, stream>>>(alpha, aH, aL, BATCH * KB);
  k_split_phiT<<<dim3(DD / 32, KB / 32), 256, 0, stream>>>(phi, pTh, pTl);
  k_xphiT<1><<<dim3(DD / 128, BATCH / 128), 256, 0, stream>>>(
      aH, aL, pTh, pTl, nullptr, reconF, DD, KB);
}

// Round 21
// 10001.817 us; speedup vs baseline: 2.9757x; 1.3886x over previous
//
#include <hip/hip_runtime.h>
#include <math.h>

#define BATCH 8192
#define KB 2048      // num basis (N of fused GEMM)
#define DD 1024      // dim basis
#define LAM 0.1f
#define N_ITER 100
#define N_POWER 50
#define NTILES 32    // K' = 2048 = 32 * 64  (fp16 1-term: yh vs Gh)

typedef unsigned short u16;
using short8 = __attribute__((ext_vector_type(8))) short;
using f32x4  = __attribute__((ext_vector_type(4))) float;

// ---------- bf16 split helpers (RNE) ----------
__device__ __forceinline__ u16 f2bf(float f) {
  unsigned int u = __builtin_bit_cast(unsigned int, f);
  u = u + 0x7FFFu + ((u >> 16) & 1u);
  return (u16)(u >> 16);
}
__device__ __forceinline__ float bf2f(u16 s) {
  unsigned int u = ((unsigned int)s) << 16;
  return __builtin_bit_cast(float, u);
}

// ---------- fp16 helpers (RNE via HW cvt) ----------
__device__ __forceinline__ u16 f2h(float f) {
  _Float16 h = (_Float16)f;
  return __builtin_bit_cast(unsigned short, h);
}
__device__ __forceinline__ float h2f(u16 s) {
  _Float16 h = __builtin_bit_cast(_Float16, s);
  return (float)h;
}

// ---------------- utility kernels ----------------
__global__ void k_split_f32(const float* __restrict__ in, u16* __restrict__ h,
                            u16* __restrict__ lo, int n) {  // bf16 pair
  for (int i = blockIdx.x * blockDim.x + threadIdx.x; i < n; i += gridDim.x * blockDim.x) {
    float v = in[i];
    u16 hh = f2bf(v);
    h[i] = hh;
    lo[i] = f2bf(v - bf2f(hh));
  }
}

// transposed bf16-pair split: th/tl[d][k] = split(phi[k][d])  (r3-proven)
__global__ __launch_bounds__(256) void k_split_phiT(const float* __restrict__ phi,
                                                    u16* __restrict__ th, u16* __restrict__ tl) {
  __shared__ float t[32][33];
  int k0 = blockIdx.y * 32, d0 = blockIdx.x * 32;
  int tx = threadIdx.x & 31, ty = threadIdx.x >> 5;  // 8 rows per pass
#pragma unroll
  for (int rr = 0; rr < 32; rr += 8)
    t[ty + rr][tx] = phi[(size_t)(k0 + ty + rr) * DD + d0 + tx];
  __syncthreads();
#pragma unroll
  for (int rr = 0; rr < 32; rr += 8) {
    float v = t[tx][ty + rr];  // = phi[k0+tx][d0+ty+rr]
    u16 hh = f2bf(v);
    size_t idx = (size_t)(d0 + ty + rr) * KB + (k0 + tx);
    th[idx] = hh;
    tl[idx] = f2bf(v - bf2f(hh));
  }
}

__global__ void k_cvt_f16(const float* __restrict__ in, u16* __restrict__ h, int n) {
  for (int i = blockIdx.x * blockDim.x + threadIdx.x; i < n; i += gridDim.x * blockDim.x)
    h[i] = f2h(in[i]);
}

// init power iteration: w = ones, partialA = 1/64 each (sum = 1 -> first norm = 1)
__global__ void k_init_pw(float* __restrict__ w, float* __restrict__ pA) {
  int i = blockIdx.x * 256 + threadIdx.x;
  if (i < KB) w[i] = 1.f;
  if (i < 64) pA[i] = 1.f / 64.f;
}

// ---------------- fused power step (r20-proven; ping-pong, no grid.sync) ----------------
template <int MODE>
__global__ __launch_bounds__(256) void k_power_fused(const float* __restrict__ G,
                                                     const float* __restrict__ win,
                                                     float* __restrict__ wout,
                                                     const float* __restrict__ pin,
                                                     float* __restrict__ pout) {
  int rloc = threadIdx.x >> 3;
  int seg = threadIdx.x & 7;
  int row = blockIdx.x * 32 + rloc;
  float n2 = 0.f;
#pragma unroll
  for (int i = 0; i < 64; ++i) n2 += pin[i];
  float n = sqrtf(n2);
  const float* g = G + (size_t)row * KB + seg * 256;
  const float* vv = win + seg * 256;
  float s = 0.f;
#pragma unroll 8
  for (int j = 0; j < 256; j += 4) {
    float4 gg = *(const float4*)(g + j);
    float4 vx = *(const float4*)(vv + j);
    s = fmaf(gg.x, vx.x, fmaf(gg.y, vx.y, fmaf(gg.z, vx.z, fmaf(gg.w, vx.w, s))));
  }
#pragma unroll
  for (int off = 1; off < 8; off <<= 1) s += __shfl_xor(s, off, 64);
  s = s / n;  // = row of G @ (win/||win||)
  float val;
  if (MODE == 0) {
    if (seg == 0) wout[row] = s;
    val = (seg == 0) ? s * s : 0.f;
  } else {
    val = (seg == 0) ? (win[row] / n) * s : 0.f;
  }
#pragma unroll
  for (int off = 8; off < 64; off <<= 1) val += __shfl_xor(val, off, 64);
  __shared__ float red[4];
  int lane = threadIdx.x & 63, wid = threadIdx.x >> 6;
  if (lane == 0) red[wid] = val;
  __syncthreads();
  if (threadIdx.x == 0) pout[blockIdx.x] = red[0] + red[1] + red[2] + red[3];
}

__global__ void k_compute_step(const float* __restrict__ partialL, float* __restrict__ stepbuf) {
  float L = 0.f;
#pragma unroll
  for (int i = 0; i < 64; ++i) L += partialL[i];
  stepbuf[0] = 1.f / L;
}

// ---------------- split-bf16 MFMA GEMM: C = A @ B^T (r3-proven body) ----------------
// EPI 0: out16[m*N+n] = fp16(acc)   (Cx)
// EPI 1: out32[m*N+n] = acc         (Gram fp32; also recon fp32)
template <int EPI>
__global__ __launch_bounds__(256) void k_xphiT(
    const u16* __restrict__ Ah, const u16* __restrict__ Al,
    const u16* __restrict__ Bh, const u16* __restrict__ Bl,
    u16* __restrict__ out16, float* __restrict__ out32, int N, int K) {
  __shared__ u16 lds[4 * 128 * 32];
  const int tid = threadIdx.x;
  const int w = tid >> 6, l = tid & 63;
  const int row0 = blockIdx.y * 128, col0 = blockIdx.x * 128;
  const int wm = (w >> 1) * 64, wn = (w & 1) * 64;
  const int lrow = l & 15, lk = (l >> 4) * 8;

  f32x4 zero4 = {0.f, 0.f, 0.f, 0.f};
  f32x4 acc[4][4];
#pragma unroll
  for (int i = 0; i < 4; ++i)
#pragma unroll
    for (int j = 0; j < 4; ++j) acc[i][j] = zero4;

  for (int k0 = 0; k0 < K; k0 += 32) {
    {
      const u16* gs[4] = {Ah, Al, Bh, Bl};
      const int r0s[4] = {row0, row0, col0, col0};
#pragma unroll
      for (int st = 0; st < 4; ++st) {
        u16* s = lds + st * 4096;
#pragma unroll
        for (int h = 0; h < 2; ++h) {
          int ch = h * 256 + w * 64 + l;
          const u16* gp = gs[st] + (size_t)(r0s[st] + (ch >> 2)) * K + k0 + (ch & 3) * 8;
          u16* sp = s + (h * 256 + w * 64) * 8;
          __builtin_amdgcn_global_load_lds((const __attribute__((address_space(1))) void*)gp,
                                           (__attribute__((address_space(3))) void*)sp, 16, 0, 0);
        }
      }
    }
    __syncthreads();
    short8 ah[4], al[4];
#pragma unroll
    for (int i = 0; i < 4; ++i) {
      int r = wm + i * 16 + lrow;
      ah[i] = *(const short8*)&lds[0 * 4096 + r * 32 + lk];
      al[i] = *(const short8*)&lds[1 * 4096 + r * 32 + lk];
    }
#pragma unroll
    for (int j = 0; j < 4; ++j) {
      int r = wn + j * 16 + lrow;
      short8 bh = *(const short8*)&lds[2 * 4096 + r * 32 + lk];
      short8 bl = *(const short8*)&lds[3 * 4096 + r * 32 + lk];
#pragma unroll
      for (int i = 0; i < 4; ++i) {
        acc[i][j] = __builtin_amdgcn_mfma_f32_16x16x32_bf16(ah[i], bh, acc[i][j], 0, 0, 0);
        acc[i][j] = __builtin_amdgcn_mfma_f32_16x16x32_bf16(ah[i], bl, acc[i][j], 0, 0, 0);
        acc[i][j] = __builtin_amdgcn_mfma_f32_16x16x32_bf16(al[i], bh, acc[i][j], 0, 0, 0);
      }
    }
    __syncthreads();
  }
#pragma unroll
  for (int i = 0; i < 4; ++i)
#pragma unroll
    for (int r = 0; r < 4; ++r) {
      int m = row0 + wm + i * 16 + ((l >> 4) << 2) + r;
      size_t base = (size_t)m * N;
#pragma unroll
      for (int j = 0; j < 4; ++j) {
        int n = col0 + wn + j * 16 + (l & 15);
        float v = acc[i][j][r];
        if (EPI == 0) {
          out16[base + n] = f2h(v);
        } else {
          out32[base + n] = v;
        }
      }
    }
}

// ---------------- iteration 0 (closed form: y=alpha=0, mu0=0; r20-proven) ----------------
__global__ void k_iter0(const u16* __restrict__ Cx, u16* __restrict__ Yout,
                        u16* __restrict__ Af16, const float* __restrict__ stepbuf) {
  const float step = stepbuf[0];
  const float thr = LAM * step;
  int n = BATCH * KB;
  for (int i = blockIdx.x * blockDim.x + threadIdx.x; i < n; i += gridDim.x * blockDim.x) {
    float z = step * h2f(Cx[i]);
    float az = fabsf(z) - thr;
    float a = az > 0.f ? copysignf(az, z) : 0.f;
    u16 ah = f2h(a);
    Af16[i] = ah;
    Yout[i] = ah;
  }
}

// ---------------- FISTA iteration (NO grid.sync: Y ping-pong across launches) ----------------
// r20 counters isolated the in-kernel grid.sync as ~60-100us of the 128us iter
// (r18: 2 syncs = 240us/iter; r17/r20: 1 sync = 128us). With Y_in/Y_out split
// there is no intra-kernel cross-block dependency (Af16 is tile-local, Cx is
// read-only), so the sync - and cooperative launch - are dropped entirely;
// the kernel boundary orders iterations (r18/r19: boundaries are the cheap sync).

__device__ __forceinline__ void stage_op(const u16* src, int r0, int q0,
                                         u16* ldsbase, int tid) {
#pragma unroll
  for (int i = 0; i < 4; ++i) {
    int c = i * 512 + tid;
    int r = c >> 3;
    int sp = (c & 7) ^ (r & 7);
    const u16* gp = src + ((size_t)(r0 + r) << 11) + (q0 + (sp << 3));
    u16* lp = ldsbase + ((i * 512 + (tid & 448)) << 3);  // wave-uniform base
    __builtin_amdgcn_global_load_lds((const __attribute__((address_space(1))) void*)gp,
                                     (__attribute__((address_space(3))) void*)lp, 16, 0, 0);
  }
}

__global__ __launch_bounds__(512, 1) void k_fista_fused(
    const u16* __restrict__ Yin, u16* __restrict__ Yout, u16* Af16,
    const u16* __restrict__ Gh,
    const u16* __restrict__ Cx, float* AlphaOut,
    const float* __restrict__ stepbuf, float mu, int last) {
  __shared__ u16 lds[65536];  // 128 KB static: [buf][A 16384 u16 | B 16384 u16]

  const int tid = threadIdx.x;
  const int w = tid >> 6, l = tid & 63;
  const int wm = w >> 2, wn = w & 3;       // 2 x 4 waves
  const int lr = l & 15, lg = l >> 4;

  // XCD-aware remap (r9-verified: FETCH 595->332 MB/iter).
  const int lin = blockIdx.x + (int)gridDim.x * blockIdx.y;  // [0,256)
  const int bq = lin >> 6;          // [0,4)
  const int bp = (lin >> 3) & 7;    // [0,8)
  const int br = lin & 7;           // [0,8)
  const int row0 = ((bq << 3) + br) * 256;  // by = 8q + r
  const int col0 = bp * 256;                // bx = p

  f32x4 acc[8][4];
  f32x4 zero4 = {0.f, 0.f, 0.f, 0.f};
#pragma unroll
  for (int i = 0; i < 8; ++i)
#pragma unroll
    for (int j = 0; j < 4; ++j) acc[i][j] = zero4;

  // prologue: stage tile 0 into buf0 only (1-tile-ahead scheme)
  stage_op(Yin, row0, 0, lds, tid);
  stage_op(Gh, col0, 0, lds + 16384, tid);

#define FBODY(TT, B)                                                              \
  {                                                                               \
    asm volatile("s_waitcnt vmcnt(0)" ::: "memory");                              \
    __builtin_amdgcn_s_barrier();                                                 \
    __builtin_amdgcn_sched_barrier(0);                                            \
    {                                                                             \
      int tn = (TT) + 1;                                                          \
      if (tn >= NTILES) tn = 0;                                                   \
      int q0 = tn << 6;                                                           \
      stage_op(Yin, row0, q0, lds + ((B) ? 0 : 32768), tid);                      \
      stage_op(Gh, col0, q0, lds + ((B) ? 0 : 32768) + 16384, tid);               \
    }                                                                             \
    __builtin_amdgcn_sched_barrier(0);                                            \
    const u16* baseA = lds + ((B) ? 32768 : 0);                                   \
    const u16* baseB = baseA + 16384;                                             \
    short8 bf[4][2];                                                              \
    _Pragma("unroll") for (int j = 0; j < 4; ++j) {                               \
      _Pragma("unroll") for (int ks = 0; ks < 2; ++ks) {                          \
        int brow = wn * 64 + j * 16 + lr;                                         \
        int slot = ks * 4 + lg;                                                   \
        bf[j][ks] = *(const short8*)(baseB + brow * 64 + ((slot ^ (brow & 7)) << 3)); \
      }                                                                           \
    }                                                                             \
    __builtin_amdgcn_s_setprio(1);                                                \
    _Pragma("unroll") for (int i = 0; i < 8; ++i) {                               \
      int arow = wm * 128 + i * 16 + lr;                                          \
      short8 a0 = *(const short8*)(baseA + arow * 64 + (((0 + lg) ^ (arow & 7)) << 3)); \
      short8 a1 = *(const short8*)(baseA + arow * 64 + (((4 + lg) ^ (arow & 7)) << 3)); \
      _Pragma("unroll") for (int j = 0; j < 4; ++j) {                             \
        acc[i][j] = __builtin_amdgcn_mfma_f32_16x16x32_f16(a0, bf[j][0], acc[i][j], 0, 0, 0); \
        acc[i][j] = __builtin_amdgcn_mfma_f32_16x16x32_f16(a1, bf[j][1], acc[i][j], 0, 0, 0); \
      }                                                                           \
    }                                                                             \
    __builtin_amdgcn_s_setprio(0);                                                \
  }

  for (int tt = 0; tt < NTILES; tt += 2) {
    FBODY(tt, 0)
    FBODY(tt + 1, 1)
  }
#undef FBODY

  // ---- epilogue (no device-wide sync needed: Yout != Yin, Af16 tile-local) ----
  const float step = stepbuf[0];
  const float thr = LAM * step;
#pragma unroll
  for (int i = 0; i < 8; ++i) {
#pragma unroll
    for (int r = 0; r < 4; ++r) {
      int m = row0 + wm * 128 + i * 16 + (lg << 2) + r;
      size_t base = (size_t)m * KB;
#pragma unroll
      for (int j = 0; j < 4; ++j) {
        int n = col0 + wn * 64 + j * 16 + lr;
        size_t idx = base + n;
        float g = acc[i][j][r] - h2f(Cx[idx]);
        float y = h2f(Yin[idx]);
        float z = y - step * g;
        float az = fabsf(z) - thr;
        float a = az > 0.f ? copysignf(az, z) : 0.f;
        float ap = h2f(Af16[idx]);
        float yn = a + mu * (a - ap);
        Af16[idx] = f2h(a);
        if (last) AlphaOut[idx] = a;
        Yout[idx] = f2h(yn);
      }
    }
  }
}

// ---------------- launch ----------------
extern "C" void kernel_launch(void* const* d_in, const int* in_sizes, int n_in,
                              void* d_out, int out_size, void* d_ws, size_t ws_size,
                              hipStream_t stream) {
  const float* x = (const float*)d_in[0];    // [8192,1024]
  const float* phi = (const float*)d_in[1];  // [2048,1024]
  float* out = (float*)d_out;
  float* alpha = out;                             // [8192*2048] fp32, written at last iter
  float* reconF = out + (size_t)BATCH * KB;       // [8192*1024] fp32 (33.55 MB scratch region)

  // ---- workspace layout (byte offsets) ----
  char* ws = (char*)d_ws;
  u16* YA = (u16*)ws;                                   // 33,554,432 B (fp16 y buffer A)
  u16* Af16 = (u16*)(ws + 33554432ull);                 // 33,554,432 B (fp16 alpha history)
  u16* Gph = (u16*)(ws + 67108864ull);                  // 8,388,608 B  (Gh fp16; temp phiH bf16)
  u16* Gpl = (u16*)(ws + 75497472ull);                  // 8,388,608 B  (temp phiL bf16)
  u16* Cx16 = (u16*)(ws + 83886080ull);                 // 33,554,432 B (fp16 Cx)
  float* Gf = (float*)(ws + 117440512ull);              // 16,777,216 B (fp32 G; later phiT splits)
  float* stepbuf = (float*)(ws + 150994944ull);         // 64 B
  const size_t need = 150995008ull;
  if (ws_size < need) return;

  // Y buffer B lives in the recon region of d_out (dead until final recon).
  u16* YB = (u16*)reconF;                               // 33,554,432 B (fp16 y buffer B)

  // pre-FISTA temporaries in recon region of d_out (dead before k_iter0):
  u16* xh = (u16*)reconF;           // x split hi [8192*1024]
  u16* xl = xh + (size_t)BATCH * DD;
  float* vA = reconF;               // power-iter ping-pong (xh/xl dead after Cx)
  float* vB = reconF + 2048;
  float* pA = reconF + 4096;        // 64 floats
  float* pB = reconF + 4224;        // 64 floats

  // 1. splits: phi -> (Gph,Gpl temp, bf16 pair), x -> (xh,xl)
  k_split_f32<<<2048, 256, 0, stream>>>(phi, Gph, Gpl, KB * DD);
  k_split_f32<<<2048, 256, 0, stream>>>(x, xh, xl, BATCH * DD);

  // 2. Cx = x @ phi^T (fp16 out), M=8192 N=2048 K=1024
  k_xphiT<0><<<dim3(KB / 128, BATCH / 128), 256, 0, stream>>>(
      xh, xl, Gph, Gpl, Cx16, nullptr, KB, DD);

  // 3. G = phi @ phi^T (fp32 out via MFMA), M=N=2048 K=1024
  k_xphiT<1><<<dim3(KB / 128, KB / 128), 256, 0, stream>>>(
      Gph, Gpl, Gph, Gpl, nullptr, Gf, KB, DD);

  // 4. power iteration: 50 fused steps (ping-pong) + Rayleigh + step (r20-proven)
  k_init_pw<<<8, 256, 0, stream>>>(vA, pA);
  for (int s = 0; s < N_POWER; ++s) {
    const float* win = (s & 1) ? vB : vA;
    float* wout = (s & 1) ? vA : vB;
    const float* pin = (s & 1) ? pB : pA;
    float* pout = (s & 1) ? pA : pB;
    k_power_fused<0><<<64, 256, 0, stream>>>(Gf, win, wout, pin, pout);
  }
  k_power_fused<1><<<64, 256, 0, stream>>>(Gf, vA, nullptr, pA, pB);
  k_compute_step<<<1, 1, 0, stream>>>(pB, stepbuf);

  // 5. Gh = fp16(G) (overwrites phiH split; dead after steps 2-3)
  k_cvt_f16<<<2048, 256, 0, stream>>>(Gf, Gph, KB * KB);

  // 6. iteration 0 closed-form -> Y into YA (power-iter scratch in YB region is dead)
  k_iter0<<<2048, 256, 0, stream>>>(Cx16, YA, Af16, stepbuf);

  // 7. FISTA iterations 1..99: plain launches, Y ping-pong (no grid.sync anywhere)
  float t = 1.f;
  float mus[N_ITER];
  for (int it = 0; it < N_ITER; ++it) {
    float tn = 0.5f * (1.f + sqrtf(1.f + 4.f * t * t));
    mus[it] = (t - 1.f) / tn;
    t = tn;
  }
  u16* ycur = YA;  // holds y_1 (written by iter 0)
  u16* ynext = YB;
  for (int it = 1; it < N_ITER; ++it) {
    int last = (it == N_ITER - 1) ? 1 : 0;
    k_fista_fused<<<dim3(KB / 256, BATCH / 256), 512, 0, stream>>>(
        ycur, ynext, Af16, Gph, Cx16, alpha, stepbuf, mus[it], last);
    u16* tmp = ycur; ycur = ynext; ynext = tmp;
  }

  // 8. recon = alpha @ phi via split-bf16 MFMA (alpha splits into dead YA/Af16;
  //    phi^T splits into dead Gf region; recon overwrites YB region afterwards)
  u16* aH = YA;                       // bf16 alpha hi
  u16* aL = Af16;                     // bf16 alpha lo
  u16* pTh = (u16*)Gf;                // bf16 phiT hi [DD][KB]
  u16* pTl = pTh + (size_t)DD * KB;   // bf16 phiT lo
  k_split_f32<<<2048, 256, 0, stream>>>(alpha, aH, aL, BATCH * KB);
  k_split_phiT<<<dim3(DD / 32, KB / 32), 256, 0, stream>>>(phi, pTh, pTl);
  k_xphiT<1><<<dim3(DD / 128, BATCH / 128), 256, 0, stream>>>(
      aH, aL, pTh, pTl, nullptr, reconF, DD, KB);
}